// Round 8
// baseline (366.778 us; speedup 1.0000x reference)
//
#include <hip/hip_runtime.h>

#define NB   2000   // N
#define HH   4      // heads
#define KK   20     // topk
#define KP   2048   // padded K (j) dim for GEMM
#define GA   4      // rows per k_scores_topk block
#define EPSF 1e-8f

typedef unsigned short ushort;
typedef unsigned long long ull;
using short8   = __attribute__((ext_vector_type(8))) short;
using floatx4  = __attribute__((ext_vector_type(4))) float;
using ushortx4 = __attribute__((ext_vector_type(4))) unsigned short;
using ushortx8 = __attribute__((ext_vector_type(8))) unsigned short;

__device__ inline ushort f2bf(float f) {
    unsigned u = __builtin_bit_cast(unsigned, f);
    u += 0x7fffu + ((u >> 16) & 1u);   // round-to-nearest-even
    return (ushort)(u >> 16);
}

__device__ __forceinline__ void gload_lds16(const ushort* g, ushort* l) {
    __builtin_amdgcn_global_load_lds(
        (const __attribute__((address_space(1))) void*)g,
        (__attribute__((address_space(3))) void*)l, 16, 0, 0);
}

// VALU-only DPP max step: x = max(x, dpp_move(x, CTRL)). Invalid source
// lanes keep old (=x), which is identity for max.
template<int CTRL>
__device__ __forceinline__ float dppmax(float x) {
    int xi = __builtin_bit_cast(int, x);
    int yi = __builtin_amdgcn_update_dpp(xi, xi, CTRL, 0xF, 0xF, false);
    return fmaxf(x, __builtin_bit_cast(float, yi));
}

// After this chain lane 63 holds the wave-wide max (gfx9 wave64 pattern).
__device__ __forceinline__ float wavemax63(float x) {
    x = dppmax<0x111>(x);   // row_shr:1
    x = dppmax<0x112>(x);   // row_shr:2
    x = dppmax<0x114>(x);   // row_shr:4
    x = dppmax<0x118>(x);   // row_shr:8
    x = dppmax<0x142>(x);   // row_bcast:15
    x = dppmax<0x143>(x);   // row_bcast:31
    return x;
}

#define COMP(v,i) ((i)==0?(v).x:(i)==1?(v).y:(i)==2?(v).z:(v).w)

// ---------------------------------------------------------------------------
// Kernel 1 (fused): scores + top-20 in score domain for GA=4 rows of one head.
// UNCHANGED (verified, ~121us anchor).
// ---------------------------------------------------------------------------
__global__ __launch_bounds__(512, 4) void k_scores_topk(
    const float* __restrict__ e1, const float* __restrict__ e2,
    const float* __restrict__ temperature,
    int* __restrict__ topk_idx, float* __restrict__ topk_val)
{
    const int h  = blockIdx.y;
    const int n0 = blockIdx.x * GA;
    const int t  = threadIdx.x;
    const int w  = t >> 6, lane = t & 63;

    __shared__ float e1s[GA][64];
    __shared__ float scoresS[GA][2048];
    __shared__ float red[GA][4];
    __shared__ ull   lists[4][GA][KK + 1];
    __shared__ float selpv[GA][KK];
    __shared__ int   seli[GA][KK];
    __shared__ float ssum[GA];

    if (t < 256)
        e1s[t >> 6][t & 63] = e1[(size_t)(h * NB + n0 + (t >> 6)) * 64 + (t & 63)];
    __syncthreads();

    const float rtemp = 1.f / temperature[h];
    const float* __restrict__ e2h = e2 + (size_t)h * 64 * NB;

    // ---- phase 1: GEMM, 8 waves, 4 cols per lane (16 accumulators) ----
    {
        const int mb1 = w * 256 + lane * 4;           // this lane's 4 cols
        const int ml1 = (mb1 < NB) ? mb1 : (NB - 4);  // clamp tail (dup cols)

        float acc[GA][4];
#pragma unroll
        for (int r = 0; r < GA; r++)
#pragma unroll
            for (int c = 0; c < 4; c++) acc[r][c] = 0.f;

        for (int d4 = 0; d4 < 64; d4 += 4) {
            float4 ev0 = *(const float4*)&e1s[0][d4];
            float4 ev1 = *(const float4*)&e1s[1][d4];
            float4 ev2 = *(const float4*)&e1s[2][d4];
            float4 ev3 = *(const float4*)&e1s[3][d4];
#pragma unroll
            for (int dd = 0; dd < 4; dd++) {
                float4 a = *(const float4*)(e2h + (size_t)(d4 + dd) * NB + ml1);
                float f0 = COMP(ev0, dd), f1 = COMP(ev1, dd);
                float f2 = COMP(ev2, dd), f3 = COMP(ev3, dd);
                acc[0][0] += f0*a.x; acc[0][1] += f0*a.y; acc[0][2] += f0*a.z; acc[0][3] += f0*a.w;
                acc[1][0] += f1*a.x; acc[1][1] += f1*a.y; acc[1][2] += f1*a.z; acc[1][3] += f1*a.w;
                acc[2][0] += f2*a.x; acc[2][1] += f2*a.y; acc[2][2] += f2*a.z; acc[2][3] += f2*a.w;
                acc[3][0] += f3*a.x; acc[3][1] += f3*a.y; acc[3][2] += f3*a.z; acc[3][3] += f3*a.w;
            }
        }

#pragma unroll
        for (int r = 0; r < GA; r++) {
            float4 v; v.x = acc[r][0]; v.y = acc[r][1]; v.z = acc[r][2]; v.w = acc[r][3];
            *(float4*)&scoresS[r][mb1] = v;   // slot by UNCLAMPED col; tail sentineled below
        }
    }
    __syncthreads();

    // ---- phases 2+3: selection, waves 0-3 only ----
    if (w < 4) {
        const int  mbase = w * 512 + lane * 8;
        const bool valid = (mbase < NB);            // all-8-or-none (NB%8==0)

        float acc[GA][8];
#pragma unroll
        for (int r = 0; r < GA; r++) {
            float4 lo = *(const float4*)&scoresS[r][mbase];
            float4 hi = *(const float4*)&scoresS[r][mbase + 4];
            acc[r][0] = lo.x; acc[r][1] = lo.y; acc[r][2] = lo.z; acc[r][3] = lo.w;
            acc[r][4] = hi.x; acc[r][5] = hi.y; acc[r][6] = hi.z; acc[r][7] = hi.w;
        }

        // tv = relu(acc)*rtemp ; invalid tail lanes -> -1 sentinel
#pragma unroll
        for (int r = 0; r < GA; r++) {
            float tvm = -1.f;
#pragma unroll
            for (int k = 0; k < 8; k++) {
                float v = valid ? fmaxf(acc[r][k], 0.f) * rtemp : -1.f;
                acc[r][k] = v;
                tvm = fmaxf(tvm, v);
            }
            tvm = wavemax63(tvm);
            if (lane == 63) red[r][w] = tvm;   // slice max (for exp shift)
        }

        // running per-lane local argmax for each row (strict > keeps lowest k)
        float lm[GA]; int ak[GA];
#pragma unroll
        for (int r = 0; r < GA; r++) {
            float l = acc[r][0]; int a = 0;
#pragma unroll
            for (int k = 1; k < 8; k++)
                if (acc[r][k] > l) { l = acc[r][k]; a = k; }
            lm[r] = l; ak[r] = a;
        }

        // selection: 20 rounds; per round all 4 rows' DPP chains interleaved
        for (int round = 0; round < KK; round++) {
            float M[GA];
#pragma unroll
            for (int r = 0; r < GA; r++) M[r] = lm[r];
#pragma unroll
            for (int r = 0; r < GA; r++) M[r] = dppmax<0x111>(M[r]);
#pragma unroll
            for (int r = 0; r < GA; r++) M[r] = dppmax<0x112>(M[r]);
#pragma unroll
            for (int r = 0; r < GA; r++) M[r] = dppmax<0x114>(M[r]);
#pragma unroll
            for (int r = 0; r < GA; r++) M[r] = dppmax<0x118>(M[r]);
#pragma unroll
            for (int r = 0; r < GA; r++) M[r] = dppmax<0x142>(M[r]);
#pragma unroll
            for (int r = 0; r < GA; r++) M[r] = dppmax<0x143>(M[r]);
#pragma unroll
            for (int r = 0; r < GA; r++)
                M[r] = __builtin_bit_cast(float,
                         __builtin_amdgcn_readlane(__builtin_bit_cast(int, M[r]), 63));
#pragma unroll
            for (int r = 0; r < GA; r++) {
                ull ball = __ballot(lm[r] == M[r]);
                int wl   = __ffsll(ball) - 1;       // lowest lane = lowest global idx
                if (lane == wl) {
                    int gidx = mbase + ak[r];
                    lists[w][r][round] =
                        ((ull)__float_as_uint(M[r]) << 32) | (unsigned)~gidx;
#pragma unroll
                    for (int k = 0; k < 8; k++) if (k == ak[r]) acc[r][k] = -2.f;
                    float l = acc[r][0]; int a = 0;
#pragma unroll
                    for (int k = 1; k < 8; k++)
                        if (acc[r][k] > l) { l = acc[r][k]; a = k; }
                    lm[r] = l; ak[r] = a;
                }
            }
        }
#pragma unroll
        for (int r = 0; r < GA; r++)
            if (lane == 0) lists[w][r][KK] = 0ULL;  // merge sentinel
    }
    __syncthreads();

    // merge 4 sorted lists per row; lanes 0..3 of wave 0 handle one row each
    if (t < GA) {
        const int r = t;
        float mx = fmaxf(fmaxf(red[r][0], red[r][1]), fmaxf(red[r][2], red[r][3]));
        int p0 = 0, p1 = 0, p2 = 0, p3 = 0;
        ull h0 = lists[0][r][0], h1 = lists[1][r][0];
        ull h2 = lists[2][r][0], h3 = lists[3][r][0];
        float ss = 0.f;
        for (int q = 0; q < KK; q++) {
            ull a_ = h0 >= h1 ? h0 : h1; int wa = h0 >= h1 ? 0 : 1;
            ull b_ = h2 >= h3 ? h2 : h3; int wb = h2 >= h3 ? 2 : 3;
            ull bk = a_ >= b_ ? a_ : b_; int bw = a_ >= b_ ? wa : wb;
            float tvv = __uint_as_float((unsigned)(bk >> 32));
            float pv  = __expf(tvv - mx);
            selpv[r][q] = pv;
            seli[r][q]  = (int)~(unsigned)bk;
            ss += pv;
            if      (bw == 0) h0 = lists[0][r][++p0];
            else if (bw == 1) h1 = lists[1][r][++p1];
            else if (bw == 2) h2 = lists[2][r][++p2];
            else              h3 = lists[3][r][++p3];
        }
        ssum[r] = ss;
    }
    __syncthreads();

    if (t < GA * KK) {
        int r = t / KK, q = t % KK;
        int o = (h * NB + n0 + r) * KK + q;
        topk_idx[o] = seli[r][q];
        topk_val[o] = selpv[r][q] / (ssum[r] + EPSF);
    }
}

// ---------------------------------------------------------------------------
// Kernel 2: final_adj row i; writes dense fp32 fadj (output) and scatters
// nonzeros into bf16 A-matrix faT_b[m=i][k=j] (pre-zeroed, K padded to 2048).
// ---------------------------------------------------------------------------
__global__ __launch_bounds__(256) void k_final_adj(
    const int* __restrict__ topk_idx, const float* __restrict__ topk_val,
    const float* __restrict__ ew1, const float* __restrict__ eb1,
    const float* __restrict__ ew2, const float* __restrict__ eb2,
    float* __restrict__ fadj_out, ushort* __restrict__ faT_b)
{
    const int i = blockIdx.x;
    const int t = threadIdx.x;

    __shared__ float rows[HH][NB];
    __shared__ float w1[32];
    __shared__ float b1[8];
    __shared__ float w2[8];
    __shared__ float b2v;

    for (int k = t; k < HH * NB; k += 256) ((float*)rows)[k] = 0.f;
    if (t < 32) w1[t] = ew1[t];
    if (t < 8)  { b1[t] = eb1[t]; w2[t] = ew2[t]; }
    if (t == 0) b2v = eb2[0];
    __syncthreads();

    if (t < HH * KK) {
        int h = t / KK, r = t % KK;
        int o = (h * NB + i) * KK + r;
        rows[h][topk_idx[o]] = topk_val[o];
    }
    __syncthreads();

#pragma unroll
    for (int k = 0; k < 8; k++) {
        int j = k * 256 + t;
        if (j < NB) {
            float f0 = rows[0][j], f1 = rows[1][j], f2 = rows[2][j], f3 = rows[3][j];
            float mean = (f0 + f1 + f2 + f3) * 0.25f;
            float outv = 0.f;
            if (mean > 0.f) {
                float ewv = b2v;
#pragma unroll
                for (int c = 0; c < 8; c++) {
                    float hid = f0 * w1[c] + f1 * w1[8 + c] + f2 * w1[16 + c] + f3 * w1[24 + c] + b1[c];
                    hid = fmaxf(hid, 0.f);
                    ewv += hid * w2[c];
                }
                float sig = 1.f / (1.f + expf(-ewv));
                outv = sig * mean;
                faT_b[(size_t)j * KP + i] = f2bf(outv);  // A[m=i][k=j] scatter
            }
            fadj_out[(size_t)i * NB + j] = outv;
        }
    }
}

// ---------------------------------------------------------------------------
// Kernel 3 (fused support+transpose): block (jt, bl), bl = b*32+l.
// Computes support[j][c] for 64 j's x 64 c's and writes the 64x64 tile
// TRANSPOSED directly into ST[c][j]. j in [2000,2048) zero-filled.
// ---------------------------------------------------------------------------
__global__ __launch_bounds__(256) void k_support_t(
    const float* __restrict__ x, const float* __restrict__ w,
    ushort* __restrict__ ST)
{
    const int jt = blockIdx.x;   // 0..31  j-tile
    const int bl = blockIdx.y;   // 0..127 (b*32 + l)
    const int b_ = bl >> 5, l = bl & 31;
    const int t  = threadIdx.x;

    __shared__ float  xs[64][65];   // [j-local][dd], 65-pad (bank spread)
    __shared__ float  ws[64 * 64];  // [dd][d]
    __shared__ ushort ob[64 * 65];  // [j-local][d] bf16, 65-pad (transpose read)

    for (int k = t; k < 4096; k += 256) ws[k] = w[k];

    {
        const float* xb = x + (size_t)b_ * 4096000 + (size_t)l * 64;
#pragma unroll
        for (int p = 0; p < 4; p++) {
            int q  = p * 256 + t;
            int jl = q >> 4, f4 = q & 15;         // j-local, float4 index
            int jg = jt * 64 + jl;
            int jc = jg < NB ? jg : (NB - 1);     // clamp OOB x read (masked later)
            *(float4*)&xs[jl][f4 * 4] =
                *(const float4*)(xb + (size_t)jc * 2048 + f4 * 4);
        }
    }
    __syncthreads();

    const int dq = t & 15;    // d-quad: d = dq*4..+4
    const int g  = t >> 4;    // j-group: j-local = g*4+r
    float acc[4][4];
#pragma unroll
    for (int r = 0; r < 4; r++)
#pragma unroll
        for (int c = 0; c < 4; c++) acc[r][c] = 0.f;

    for (int dd = 0; dd < 64; dd++) {
        float4 w4 = *(const float4*)&ws[dd * 64 + dq * 4];
#pragma unroll
        for (int r = 0; r < 4; r++) {
            float xv = xs[g * 4 + r][dd];
            acc[r][0] += xv * w4.x;
            acc[r][1] += xv * w4.y;
            acc[r][2] += xv * w4.z;
            acc[r][3] += xv * w4.w;
        }
    }

    // bf16-convert into LDS tile; zero rows for j >= NB (ST padding)
#pragma unroll
    for (int r = 0; r < 4; r++) {
        int jl = g * 4 + r;
        bool jvalid = (jt * 64 + jl) < NB;
        ushort* dst = &ob[jl * 65 + dq * 4];
        dst[0] = jvalid ? f2bf(acc[r][0]) : (ushort)0;
        dst[1] = jvalid ? f2bf(acc[r][1]) : (ushort)0;
        dst[2] = jvalid ? f2bf(acc[r][2]) : (ushort)0;
        dst[3] = jvalid ? f2bf(acc[r][3]) : (ushort)0;
    }
    __syncthreads();

    // transposed write: ST[c][j], c = bl*64 + rc, j = jt*64 + s*8..+8
#pragma unroll
    for (int p = 0; p < 2; p++) {
        int q = p * 256 + t;
        int rc = q >> 3, s = q & 7;
        ushortx8 o;
#pragma unroll
        for (int k = 0; k < 8; k++) o[k] = ob[(s * 8 + k) * 65 + rc];
        *(ushortx8*)&ST[(size_t)(bl * 64 + rc) * KP + jt * 64 + s * 8] = o;
    }
}

// ---------------------------------------------------------------------------
// Kernel 4: MFMA bf16 GEMM: out[i][c] = sum_j A[i][j] * B[c][j]
// 256x256 tile, 8 waves, double-buffered LDS.
// THIS ROUND: 4-phase interleaved schedule (T3+T5 port of the m201 recipe):
// each K-tile's 64 MFMA split into 4 phases of 16 (2 af-rows x 4 bf-cols x
// 2 kk). Per phase: {ds_read subtile, stage 1 chunk-pair of tile kb+1,
// barrier, lgkmcnt(0), setprio(1), 16 MFMA, setprio(0), barrier}. Counted
// vmcnt ledger (uniform every tile): entry = 8 outstanding (tile kb's,
// issued during kb-1); ph0 issues pair#0 of kb+1 (+2=10) then vmcnt(2) =
// tile kb's 8 landed, 2 newest in flight; ph1-3 issue pairs #1-3 (at most
// 8 outstanding at tile end). Never drains to 0 in the main loop (the m97
// disease); last tile waits vmcnt(0). Buffer-reuse safety: readers of buf X
// (tile kb-1) retire before the trailing barrier every wave passes before
// any wave stages into X (tile kb+1). All control flow wave-uniform ->
// barrier counts align. sched_barrier(0) after every inline-asm wait
// (learn_hip rule #18). XOR swizzle unchanged (conflict-free reads).
// ---------------------------------------------------------------------------
__global__ __launch_bounds__(512, 2) void k_gemm(
    const ushort* __restrict__ A, const ushort* __restrict__ B,
    const float* __restrict__ bias, float* __restrict__ out)
{
    __shared__ ushort As[2][256 * 64];   // 64 KB
    __shared__ ushort Bs[2][256 * 64];   // 64 KB

    const int t    = threadIdx.x;
    const int lane = t & 63, wave = t >> 6;   // 8 waves
    const int wm   = wave & 1;                // M half   (128 rows)
    const int wn   = wave >> 1;               // N quarter (64 cols)

    // XCD swizzle (nwg=256, 256%8==0, cpx=32)
    const int lin = blockIdx.y * 8 + blockIdx.x;
    const int swz = (lin & 7) * 32 + (lin >> 3);
    const int i0  = (swz & 7) * 256;
    const int c0  = (swz >> 3) * 256;

    const int lr   = lane >> 3;   // local row within 8-row chunk
    const int dg   = lane & 7;    // LDS dest group (lane-linear DMA)
    const int ln15 = lane & 15;
    const int dsw0 = ((lane >> 4) + 0) ^ (lane & 7);   // k-group swizzle, kk=0
    const int dsw1 = ((lane >> 4) + 4) ^ (lane & 7);   // k-group swizzle, kk=1

    floatx4 acc[8][4];
#pragma unroll
    for (int r = 0; r < 8; r++)
#pragma unroll
        for (int c = 0; c < 4; c++) acc[r][c] = (floatx4)(0.f);

    // stage chunk-pair p_ (A+B rows wave*32+p_*8 .. +8) of K-tile kb_ into buf
#define STAGE_PAIR(buf, kb_, p_)                                               \
    {                                                                          \
        int rowb = wave * 32 + (p_) * 8;                                       \
        int row  = rowb + lr;                                                  \
        int g    = dg ^ lr;                                                    \
        gload_lds16(&A[(size_t)(i0 + row) * KP + (kb_) * 64 + g * 8],          \
                    &As[buf][rowb * 64]);                                      \
        gload_lds16(&B[(size_t)(c0 + row) * KP + (kb_) * 64 + g * 8],          \
                    &Bs[buf][rowb * 64]);                                      \
    }

    // prologue: tile 0 fully staged into buf 0 (8 loads outstanding)
#pragma unroll
    for (int p = 0; p < 4; p++) STAGE_PAIR(0, 0, p);

    for (int kb = 0; kb < 32; kb++) {
        const int cur = kb & 1;
        const int nxt = cur ^ 1;
        short8 bf0[4], bf1[4];

#pragma unroll
        for (int p = 0; p < 4; p++) {
            short8 a0k0, a0k1, a1k0, a1k1;
            const int m0 = wm * 128 + (2 * p) * 16 + ln15;
            const int m1 = m0 + 16;

            if (p == 0) {
                // stage pair#0 of next tile, then counted wait on THIS tile
                if (kb < 31) {
                    STAGE_PAIR(nxt, kb + 1, 0);
                    asm volatile("s_waitcnt vmcnt(2)" ::: "memory");
                } else {
                    asm volatile("s_waitcnt vmcnt(0)" ::: "memory");
                }
                __builtin_amdgcn_s_barrier();        // all waves: tile kb landed
                __builtin_amdgcn_sched_barrier(0);
                // ds_read: bf full tile-K (8) + af rows 0,1 (4)
#pragma unroll
                for (int c = 0; c < 4; c++) {
                    int m = wn * 64 + c * 16 + ln15;
                    bf0[c] = *(const short8*)&Bs[cur][m * 64 + dsw0 * 8];
                    bf1[c] = *(const short8*)&Bs[cur][m * 64 + dsw1 * 8];
                }
                a0k0 = *(const short8*)&As[cur][m0 * 64 + dsw0 * 8];
                a0k1 = *(const short8*)&As[cur][m0 * 64 + dsw1 * 8];
                a1k0 = *(const short8*)&As[cur][m1 * 64 + dsw0 * 8];
                a1k1 = *(const short8*)&As[cur][m1 * 64 + dsw1 * 8];
            } else {
                // ds_read af rows 2p,2p+1 (cur ready since tile start)
                a0k0 = *(const short8*)&As[cur][m0 * 64 + dsw0 * 8];
                a0k1 = *(const short8*)&As[cur][m0 * 64 + dsw1 * 8];
                a1k0 = *(const short8*)&As[cur][m1 * 64 + dsw0 * 8];
                a1k1 = *(const short8*)&As[cur][m1 * 64 + dsw1 * 8];
                if (kb < 31) STAGE_PAIR(nxt, kb + 1, p);
                __builtin_amdgcn_s_barrier();        // lockstep phase boundary
            }

            asm volatile("s_waitcnt lgkmcnt(0)" ::: "memory");
            __builtin_amdgcn_sched_barrier(0);
            __builtin_amdgcn_s_setprio(1);
#pragma unroll
            for (int c = 0; c < 4; c++) {
                acc[2 * p][c]     = __builtin_amdgcn_mfma_f32_16x16x32_bf16(a0k0, bf0[c], acc[2 * p][c], 0, 0, 0);
                acc[2 * p][c]     = __builtin_amdgcn_mfma_f32_16x16x32_bf16(a0k1, bf1[c], acc[2 * p][c], 0, 0, 0);
                acc[2 * p + 1][c] = __builtin_amdgcn_mfma_f32_16x16x32_bf16(a1k0, bf0[c], acc[2 * p + 1][c], 0, 0, 0);
                acc[2 * p + 1][c] = __builtin_amdgcn_mfma_f32_16x16x32_bf16(a1k1, bf1[c], acc[2 * p + 1][c], 0, 0, 0);
            }
            __builtin_amdgcn_s_setprio(0);
            __builtin_amdgcn_s_barrier();            // readers done -> next stage safe
        }
    }
#undef STAGE_PAIR

    // epilogue: D layout col = lane&15, row = (lane>>4)*4 + reg  [m89-verified]
    const int mq = (lane >> 4) * 4;
    const int nn = lane & 15;
#pragma unroll
    for (int r = 0; r < 8; r++) {
#pragma unroll
        for (int c = 0; c < 4; c++) {
            int cg = c0 + wn * 64 + c * 16 + nn;
            float bv = bias[cg & 63];
            int b_ = cg >> 11, rem = cg & 2047;
            float* op = out + (size_t)b_ * 4096000 + rem;
#pragma unroll
            for (int rg = 0; rg < 4; rg++) {
                int i = i0 + wm * 128 + r * 16 + mq + rg;
                if (i < NB) op[(size_t)i * 2048] = acc[r][c][rg] + bv;
            }
        }
    }
}

// ---------------------------------------------------------------------------
extern "C" void kernel_launch(void* const* d_in, const int* in_sizes, int n_in,
                              void* d_out, int out_size, void* d_ws, size_t ws_size,
                              hipStream_t stream)
{
    const float* x           = (const float*)d_in[0];
    const float* e1          = (const float*)d_in[1];
    const float* e2          = (const float*)d_in[2];
    const float* temperature = (const float*)d_in[3];
    const float* ew1         = (const float*)d_in[4];
    const float* eb1         = (const float*)d_in[5];
    const float* ew2         = (const float*)d_in[6];
    const float* eb2         = (const float*)d_in[7];
    const float* weight      = (const float*)d_in[8];
    const float* bias        = (const float*)d_in[9];

    float* out  = (float*)d_out;            // (B,N,L,DOUT) = 16,384,000 floats
    float* fadj = out + 16384000;           // (N,N)        =  4,000,000 floats

    // workspace:
    //   ST    bf16 8192xKP = 33,554,432 B
    //   faT_b bf16 KPxKP   =  8,388,608 B
    //   topk  idx+val      =  1,280,000 B      total ~43.2 MB
    ushort* ST       = (ushort*)d_ws;
    ushort* faT_b    = ST + (size_t)8192 * KP;
    int*    topk_idx = (int*)(faT_b + (size_t)KP * KP);
    float*  topk_val = (float*)(topk_idx + 160000);

    hipMemsetAsync(faT_b, 0, (size_t)KP * KP * sizeof(ushort), stream);

    k_scores_topk<<<dim3(NB / GA, HH), 512, 0, stream>>>(e1, e2, temperature,
                                                         topk_idx, topk_val);
    k_final_adj<<<NB, 256, 0, stream>>>(topk_idx, topk_val, ew1, eb1, ew2, eb2,
                                        fadj, faT_b);
    k_support_t<<<dim3(32, 128), 256, 0, stream>>>(x, weight, ST);
    k_gemm<<<dim3(8, 32), 512, 0, stream>>>(faT_b, ST, bias, out);
}